// Round 5
// baseline (325.903 us; speedup 1.0000x reference)
//
#include <hip/hip_runtime.h>
#include <cstdint>

typedef __bf16 bf16_t;
typedef __bf16 bf16x8 __attribute__((ext_vector_type(8)));
typedef float f32x4 __attribute__((ext_vector_type(4)));

// ---- geometry constants ----
#define BT_   128
#define LTOK  197
#define CIN   768
#define CA_   384
#define TT    16
#define HH    14
#define NTOK  25088   // 128*196

// ---------------- prep: fold 3 convs + identity into one 3x3x3 kernel ----------------
__global__ void prep_weights_kernel(
    const float* __restrict__ c1w, const float* __restrict__ c1b,
    const float* __restrict__ c2w, const float* __restrict__ c2b,
    const float* __restrict__ c3w, const float* __restrict__ c3b,
    const float* __restrict__ projw,
    bf16_t* __restrict__ Wtb,    // [27][384]
    float* __restrict__ beff,    // [384]
    float* __restrict__ pwt) {   // [3][384]
  int a = blockIdx.x * blockDim.x + threadIdx.x;
  if (a >= CA_) return;
  for (int dt = 0; dt < 3; dt++)
    for (int dh = 0; dh < 3; dh++)
      for (int dw = 0; dw < 3; dw++) {
        float v = c3w[a*27 + dt*9 + dh*3 + dw];
        if (dh == 1 && dw == 1) v += c1w[a*3 + dt];
        if (dt == 1)            v += c2w[a*9 + dh*3 + dw];
        v *= (1.0f/3.0f);
        if (dt == 1 && dh == 1 && dw == 1) v += 1.0f;   // + identity
        Wtb[((dt*3+dh)*3+dw)*CA_ + a] = (bf16_t)v;
      }
  beff[a] = (c1b[a] + c2b[a] + c3b[a]) * (1.0f/3.0f);
  pwt[0*CA_ + a] = projw[a*3 + 0];
  pwt[1*CA_ + a] = projw[a*3 + 1];
  pwt[2*CA_ + a] = projw[a*3 + 2];
}

// convert fc weights into MFMA-fragment-linear layout + copy CLS rows of x into out.
// Frag layout: frag f holds a 16-col x 32-k B-tile; lane l supplies
// B[col = cb*16 + (l&15)][k = ch*32 + (l>>4)*8 + j], j=0..7 -> elem f*512 + l*8 + j.
// W1f: f = ch*24 + cb (ch<24, cb<24).  W2f: f = ch*48 + cb (ch<12, cb<48).
__global__ void convert_w_kernel(const float* __restrict__ fc1w,
                                 const float* __restrict__ fc2w,
                                 const float* __restrict__ x,
                                 float* __restrict__ out,
                                 bf16_t* __restrict__ W1f,
                                 bf16_t* __restrict__ W2f) {
  int i = blockIdx.x * blockDim.x + threadIdx.x;
  if (i < CA_*CIN) {
    int f = i >> 9, t = i & 511, l = t >> 3, j = t & 7;
    int ch = f / 24, cb = f % 24;
    int col = cb*16 + (l & 15);
    int k   = ch*32 + (l >> 4)*8 + j;
    W1f[i] = (bf16_t)fc1w[col*CIN + k];
    return;
  }
  i -= CA_*CIN;
  if (i < CIN*CA_) {
    int f = i >> 9, t = i & 511, l = t >> 3, j = t & 7;
    int ch = f / 48, cb = f % 48;
    int col = cb*16 + (l & 15);
    int k   = ch*32 + (l >> 4)*8 + j;
    W2f[i] = (bf16_t)fc2w[col*CA_ + k];
    return;
  }
  i -= CIN*CA_;
  if (i < BT_*CIN) {
    int bt = i / CIN, c = i % CIN;
    size_t off = (size_t)bt * LTOK * CIN + c;
    out[off] = x[off];
  }
}

// ---------------- GEMM1: H0[tok,a] = bf16( x_tokens[tok,:] . fc1_w[a,:] + fc1_b[a] ) ----------------
// One wave per block, 64x96 output tile. ZERO LDS, ZERO barriers:
// A (x rows, f32) loaded direct global->reg and converted; B frags loaded direct
// from L2-resident fragment-linear W1f. Fully unrolled; compiler pipelines freely.
__global__ __launch_bounds__(64) void gemm1_kernel(
    const float* __restrict__ x, const bf16_t* __restrict__ W1f,
    const float* __restrict__ fc1b, bf16_t* __restrict__ H0) {
  const int lane = threadIdx.x;
  const int wg = blockIdx.x;          // 0..3  -> N-offset wg*96
  const int bm = blockIdx.y;          // 0..391 -> M-offset bm*64
  const int quad = lane >> 4, r16 = lane & 15;
  const int wn = wg * 96;

  const float* xa[4];
  #pragma unroll
  for (int mt = 0; mt < 4; mt++) {
    int tok = bm*64 + mt*16 + r16;
    int bt = tok / 196;
    xa[mt] = x + (size_t)(tok + bt + 1)*CIN + quad*8;
  }
  const bf16_t* wb = W1f + (size_t)(wg*6)*512 + lane*8;

  f32x4 acc[4][6] = {};
  #pragma unroll
  for (int i = 0; i < 24; i++) {
    bf16x8 bfr[6];
    #pragma unroll
    for (int nt = 0; nt < 6; nt++)
      bfr[nt] = *(const bf16x8*)(wb + (size_t)(i*24 + nt)*512);
    bf16x8 af[4];
    #pragma unroll
    for (int mt = 0; mt < 4; mt++) {
      const float4* p = (const float4*)(xa[mt] + i*32);
      float4 u = p[0], v = p[1];
      af[mt][0]=(bf16_t)u.x; af[mt][1]=(bf16_t)u.y; af[mt][2]=(bf16_t)u.z; af[mt][3]=(bf16_t)u.w;
      af[mt][4]=(bf16_t)v.x; af[mt][5]=(bf16_t)v.y; af[mt][6]=(bf16_t)v.z; af[mt][7]=(bf16_t)v.w;
    }
    #pragma unroll
    for (int mt = 0; mt < 4; mt++)
      #pragma unroll
      for (int nt = 0; nt < 6; nt++)
        acc[mt][nt] = __builtin_amdgcn_mfma_f32_16x16x32_bf16(af[mt], bfr[nt], acc[mt][nt], 0, 0, 0);
  }

  #pragma unroll
  for (int nt = 0; nt < 6; nt++) {
    const int col = wn + nt*16 + r16;
    const float bias = fc1b[col];
    #pragma unroll
    for (int mt = 0; mt < 4; mt++) {
      const int row0 = bm*64 + mt*16 + quad*4;
      #pragma unroll
      for (int rg = 0; rg < 4; rg++)
        H0[(size_t)(row0 + rg)*CA_ + col] = (bf16_t)(acc[mt][nt][rg] + bias);
    }
  }
}

// ---------------- fused conv v4: register-local temporal scatter, XCD-swizzled ----------------
__global__ __launch_bounds__(192) void conv_kernel(
    const bf16_t* __restrict__ H0,
    const bf16_t* __restrict__ Wtb,   // [27][384] bf16
    const float* __restrict__ beff,   // [384]
    const float* __restrict__ pwt,    // [3][384]
    const float* __restrict__ pb,     // [384]
    bf16_t* __restrict__ Z) {
  __shared__ bf16_t Wlds[27*CA_];     // 20736 B
  __shared__ float  ybuf[2][2][CA_];  // 6144 B

  const int tid = threadIdx.x;
  {
    const uint4* src = (const uint4*)Wtb;
    uint4* dst = (uint4*)Wlds;
    #pragma unroll
    for (int i = 0; i < 7; i++) {
      int idx = tid + i*192;
      if (idx < 27*CA_/8) dst[idx] = src[idx];   // 1296 x 16B
    }
  }

  const int blk  = blockIdx.x;       // 0..783
  const int b    = blk & 7;
  const int pair = blk >> 3;         // 0..97
  const int cg   = tid % 48;
  const int ct   = tid / 48;         // 0..3
  const int col  = ct >> 1;
  const int th   = ct & 1;
  const int hw   = pair*2 + col;     // 0..195
  const int h    = hw / HH, w = hw % HH;
  const int c0   = cg * 8;
  const int t0   = th * 8;

  // init y with effective bias
  float y[8][8];
  {
    f32x4 bv0 = *(const f32x4*)(beff + c0);
    f32x4 bv1 = *(const f32x4*)(beff + c0 + 4);
    #pragma unroll
    for (int i = 0; i < 8; i++) {
      #pragma unroll
      for (int c = 0; c < 4; c++) { y[i][c] = bv0[c]; y[i][c+4] = bv1[c]; }
    }
  }

  __syncthreads();   // Wlds ready

  const size_t rowstride = (size_t)196*CA_;   // elements per t-step
  const bf16_t* base_t0 = H0 + ((size_t)(b*TT + t0)*196)*CA_ + c0;
  const int tau_e_off = th ? -1 : 8;          // the one extra valid tau (relative to t0)

  for (int j = 0; j < 9; j++) {
    const int dh = j / 3, dw = j - dh*3;
    const int h2 = h + dh - 1, w2 = w + dw - 1;
    const bool ok = ((unsigned)h2 < HH) && ((unsigned)w2 < HH);
    const int sp = ok ? (h2*HH + w2) : hw;    // clamped, always in-bounds
    const float m = ok ? 1.0f : 0.0f;

    const bf16x8 wv0 = *(const bf16x8*)&Wlds[(0*9+j)*CA_ + c0];
    const bf16x8 wv1 = *(const bf16x8*)&Wlds[(1*9+j)*CA_ + c0];
    const bf16x8 wv2 = *(const bf16x8*)&Wlds[(2*9+j)*CA_ + c0];
    float mw0[8], mw1[8], mw2[8];
    #pragma unroll
    for (int c = 0; c < 8; c++) {
      mw0[c] = m * (float)wv0[c];
      mw1[c] = m * (float)wv1[c];
      mw2[c] = m * (float)wv2[c];
    }

    const bf16_t* tp = base_t0 + (size_t)sp*CA_;
    bf16x8 gv[8];
    #pragma unroll
    for (int i = 0; i < 8; i++)
      gv[i] = *(const bf16x8*)(tp + (ptrdiff_t)i*(ptrdiff_t)rowstride);
    const bf16x8 ge = *(const bf16x8*)(tp + (ptrdiff_t)tau_e_off*(ptrdiff_t)rowstride);

    // interior taus: tau = t0+i contributes to y[i-1] (w2), y[i] (w1), y[i+1] (w0)
    #pragma unroll
    for (int i = 0; i < 8; i++) {
      float gf[8];
      #pragma unroll
      for (int c = 0; c < 8; c++) gf[c] = (float)gv[i][c];
      #pragma unroll
      for (int c = 0; c < 8; c++) y[i][c] += gf[c]*mw1[c];
      if (i > 0) {
        #pragma unroll
        for (int c = 0; c < 8; c++) y[i-1][c] += gf[c]*mw2[c];
      }
      if (i < 7) {
        #pragma unroll
        for (int c = 0; c < 8; c++) y[i+1][c] += gf[c]*mw0[c];
      }
    }
    // edge tau: th=0 -> tau=t0+8 feeds y[7] via w2 ; th=1 -> tau=t0-1 feeds y[0] via w0
    {
      float gf[8];
      #pragma unroll
      for (int c = 0; c < 8; c++) gf[c] = (float)ge[c];
      if (th) {
        #pragma unroll
        for (int c = 0; c < 8; c++) y[0][c] += gf[c]*mw0[c];
      } else {
        #pragma unroll
        for (int c = 0; c < 8; c++) y[7][c] += gf[c]*mw2[c];
      }
    }
  }

  // exchange the boundary y between t-halves (for the temporal proj)
  #pragma unroll
  for (int c = 0; c < 8; c++) ybuf[col][th][c0+c] = th ? y[0][c] : y[7][c];
  __syncthreads();
  float yedge[8];
  #pragma unroll
  for (int c = 0; c < 8; c++) yedge[c] = ybuf[col][1-th][c0+c];

  // proj weights
  float p0[8], p1[8], p2[8], pbv[8];
  {
    f32x4 a0 = *(const f32x4*)(pwt + 0*CA_ + c0), a1 = *(const f32x4*)(pwt + 0*CA_ + c0 + 4);
    f32x4 b0 = *(const f32x4*)(pwt + 1*CA_ + c0), b1 = *(const f32x4*)(pwt + 1*CA_ + c0 + 4);
    f32x4 d0 = *(const f32x4*)(pwt + 2*CA_ + c0), d1 = *(const f32x4*)(pwt + 2*CA_ + c0 + 4);
    f32x4 e0 = *(const f32x4*)(pb + c0),          e1 = *(const f32x4*)(pb + c0 + 4);
    #pragma unroll
    for (int c = 0; c < 4; c++) {
      p0[c]=a0[c]; p0[c+4]=a1[c];
      p1[c]=b0[c]; p1[c+4]=b1[c];
      p2[c]=d0[c]; p2[c+4]=d1[c];
      pbv[c]=e0[c]; pbv[c+4]=e1[c];
    }
  }

  bf16_t* zbase = Z + ((size_t)(b*TT + t0)*196 + hw)*CA_ + c0;
  #pragma unroll
  for (int i = 0; i < 8; i++) {
    bf16x8 zo;
    #pragma unroll
    for (int c = 0; c < 8; c++) {
      const float ym = (i > 0) ? y[i-1][c] : (th ? yedge[c] : 0.f);
      const float yp = (i < 7) ? y[i+1][c] : (th ? 0.f : yedge[c]);
      const float z  = y[i][c] + pbv[c] + p0[c]*ym + p1[c]*y[i][c] + p2[c]*yp;
      zo[c] = (bf16_t)z;
    }
    *(bf16x8*)(zbase + (size_t)i*rowstride) = zo;
  }
}

// ---------------- GEMM2: out[xrow,c] = x[xrow,c] + Z[tok,:] . fc2_w[c,:] + fc2_b[c] ----------------
// One wave per block, 64x96 tile, zero LDS / zero barriers. A = Z (bf16) direct
// frag loads (16B/lane); B = L2-resident fragment-linear W2f.
__global__ __launch_bounds__(64) void gemm2_kernel(
    const bf16_t* __restrict__ Z, const bf16_t* __restrict__ W2f,
    const float* __restrict__ fc2b, const float* __restrict__ x,
    float* __restrict__ out) {
  const int lane = threadIdx.x;
  const int wg = blockIdx.x;          // 0..7  -> N-offset wg*96
  const int bm = blockIdx.y;          // 0..391
  const int quad = lane >> 4, r16 = lane & 15;
  const int wn = wg * 96;

  const bf16_t* za[4];
  #pragma unroll
  for (int mt = 0; mt < 4; mt++) {
    int tok = bm*64 + mt*16 + r16;
    za[mt] = Z + (size_t)tok*CA_ + quad*8;
  }
  const bf16_t* wb = W2f + (size_t)(wg*6)*512 + lane*8;

  f32x4 acc[4][6] = {};
  #pragma unroll
  for (int i = 0; i < 12; i++) {
    bf16x8 bfr[6];
    #pragma unroll
    for (int nt = 0; nt < 6; nt++)
      bfr[nt] = *(const bf16x8*)(wb + (size_t)(i*48 + nt)*512);
    bf16x8 af[4];
    #pragma unroll
    for (int mt = 0; mt < 4; mt++)
      af[mt] = *(const bf16x8*)(za[mt] + i*32);
    #pragma unroll
    for (int mt = 0; mt < 4; mt++)
      #pragma unroll
      for (int nt = 0; nt < 6; nt++)
        acc[mt][nt] = __builtin_amdgcn_mfma_f32_16x16x32_bf16(af[mt], bfr[nt], acc[mt][nt], 0, 0, 0);
  }

  #pragma unroll
  for (int mt = 0; mt < 4; mt++) {
    #pragma unroll
    for (int rg = 0; rg < 4; rg++) {
      const int tok = bm*64 + mt*16 + quad*4 + rg;
      const int bt = tok / 196;
      const size_t rowo = (size_t)(tok + bt + 1)*CIN;
      #pragma unroll
      for (int nt = 0; nt < 6; nt++) {
        const int col = wn + nt*16 + r16;
        const size_t o = rowo + col;
        out[o] = x[o] + acc[mt][nt][rg] + fc2b[col];
      }
    }
  }
}

extern "C" void kernel_launch(void* const* d_in, const int* in_sizes, int n_in,
                              void* d_out, int out_size, void* d_ws, size_t ws_size,
                              hipStream_t stream) {
  (void)in_sizes; (void)n_in; (void)out_size; (void)ws_size;
  const float* x    = (const float*)d_in[0];
  const float* fc1w = (const float*)d_in[1];
  const float* fc1b = (const float*)d_in[2];
  const float* c1w  = (const float*)d_in[3];
  const float* c1b  = (const float*)d_in[4];
  const float* c2w  = (const float*)d_in[5];
  const float* c2b  = (const float*)d_in[6];
  const float* c3w  = (const float*)d_in[7];
  const float* c3b  = (const float*)d_in[8];
  const float* pw   = (const float*)d_in[9];
  const float* pb   = (const float*)d_in[10];
  const float* fc2w = (const float*)d_in[11];
  const float* fc2b = (const float*)d_in[12];
  float* out = (float*)d_out;

  char* ws = (char*)d_ws;
  bf16_t* W2f  = (bf16_t*)(ws);                    // 589824 B
  bf16_t* Wtb  = (bf16_t*)(ws + 589824);           // 20736
  float*  beff = (float*) (ws + 610560);           // 1536
  float*  pwt  = (float*) (ws + 612096);           // 4608
  bf16_t* H0   = (bf16_t*)(ws + 616704);           // 19267584
  bf16_t* Z    = (bf16_t*)(ws + 19884288);         // 19267584 -> end 39151872
  bf16_t* W1f  = (bf16_t*)(ws + 19884288);         // aliases Z: dead before conv writes Z
  // total ws use: 39151872 bytes

  prep_weights_kernel<<<dim3(2), dim3(192), 0, stream>>>(
      c1w, c1b, c2w, c2b, c3w, c3b, pw, Wtb, beff, pwt);
  convert_w_kernel<<<dim3(2688), dim3(256), 0, stream>>>(fc1w, fc2w, x, out, W1f, W2f);
  gemm1_kernel<<<dim3(4, 392), dim3(64), 0, stream>>>(x, W1f, fc1b, H0);
  conv_kernel<<<dim3(784), dim3(192), 0, stream>>>(H0, Wtb, beff, pwt, pb, Z);
  gemm2_kernel<<<dim3(8, 392), dim3(64), 0, stream>>>(Z, W2f, fc2b, x, out);
}

// Round 6
// 266.313 us; speedup vs baseline: 1.2238x; 1.2238x over previous
//
#include <hip/hip_runtime.h>
#include <cstdint>

typedef __bf16 bf16_t;
typedef __bf16 bf16x4 __attribute__((ext_vector_type(4)));
typedef __bf16 bf16x8 __attribute__((ext_vector_type(8)));
typedef float f32x4 __attribute__((ext_vector_type(4)));

// ---- geometry constants ----
#define BT_   128
#define LTOK  197
#define CIN   768
#define CA_   384
#define TT    16
#define HH    14
#define NTOK  25088   // 128*196

__device__ __forceinline__ void gl_lds16(const void* g, void* l) {
  __builtin_amdgcn_global_load_lds(
      (const __attribute__((address_space(1))) unsigned int*)g,
      (__attribute__((address_space(3))) unsigned int*)l,
      16, 0, 0);
}

// ---------------- prep: fold 3 convs + identity into one 3x3x3 kernel ----------------
__global__ void prep_weights_kernel(
    const float* __restrict__ c1w, const float* __restrict__ c1b,
    const float* __restrict__ c2w, const float* __restrict__ c2b,
    const float* __restrict__ c3w, const float* __restrict__ c3b,
    const float* __restrict__ projw,
    bf16_t* __restrict__ Wtb,    // [27][384]
    float* __restrict__ beff,    // [384]
    float* __restrict__ pwt) {   // [3][384]
  int a = blockIdx.x * blockDim.x + threadIdx.x;
  if (a >= CA_) return;
  for (int dt = 0; dt < 3; dt++)
    for (int dh = 0; dh < 3; dh++)
      for (int dw = 0; dw < 3; dw++) {
        float v = c3w[a*27 + dt*9 + dh*3 + dw];
        if (dh == 1 && dw == 1) v += c1w[a*3 + dt];
        if (dt == 1)            v += c2w[a*9 + dh*3 + dw];
        v *= (1.0f/3.0f);
        if (dt == 1 && dh == 1 && dw == 1) v += 1.0f;   // + identity
        Wtb[((dt*3+dh)*3+dw)*CA_ + a] = (bf16_t)v;
      }
  beff[a] = (c1b[a] + c2b[a] + c3b[a]) * (1.0f/3.0f);
  pwt[0*CA_ + a] = projw[a*3 + 0];
  pwt[1*CA_ + a] = projw[a*3 + 1];
  pwt[2*CA_ + a] = projw[a*3 + 2];
}

// ---------------- convert: W->bf16, x token rows -> bf16 xb (compact), CLS rows -> out ----
// Pure streaming, grid-stride, float4-in / bf16x4-out. ~116 MB total.
__global__ __launch_bounds__(256) void convert_w_kernel(
    const float* __restrict__ fc1w, const float* __restrict__ fc2w,
    const float* __restrict__ x, float* __restrict__ out,
    bf16_t* __restrict__ W1, bf16_t* __restrict__ W2,
    bf16_t* __restrict__ xb) {
  const int NW1 = CA_*CIN/4;        // 73728
  const int NW2 = CIN*CA_/4;        // 73728
  const int NX  = BT_*LTOK*CIN/4;   // 4841472
  const int total = NW1 + NW2 + NX;
  for (int i = blockIdx.x*256 + threadIdx.x; i < total; i += gridDim.x*256) {
    if (i < NW1) {
      float4 v = ((const float4*)fc1w)[i];
      bf16x4 b; b[0]=(bf16_t)v.x; b[1]=(bf16_t)v.y; b[2]=(bf16_t)v.z; b[3]=(bf16_t)v.w;
      *(bf16x4*)(W1 + (size_t)i*4) = b;
    } else if (i < NW1 + NW2) {
      int j = i - NW1;
      float4 v = ((const float4*)fc2w)[j];
      bf16x4 b; b[0]=(bf16_t)v.x; b[1]=(bf16_t)v.y; b[2]=(bf16_t)v.z; b[3]=(bf16_t)v.w;
      *(bf16x4*)(W2 + (size_t)j*4) = b;
    } else {
      int j = i - NW1 - NW2;        // float4 index into x
      int row = j / 192;            // 192 float4 per 768-ch row
      int c4  = j - row*192;
      int l   = row % 197;
      float4 v = ((const float4*)x)[(size_t)j];
      if (l == 0) {
        ((float4*)out)[(size_t)j] = v;   // CLS residual passthrough
      } else {
        int tok = (row/197)*196 + (l - 1);
        bf16x4 b; b[0]=(bf16_t)v.x; b[1]=(bf16_t)v.y; b[2]=(bf16_t)v.z; b[3]=(bf16_t)v.w;
        *(bf16x4*)(xb + (size_t)tok*CIN + c4*4) = b;
      }
    }
  }
}

// ---------------- GEMM1: H0[tok,a] = bf16( xb[tok,:] . fc1_w[a,:] + fc1_b[a] ) ----------------
// Structure = r1 gemm2 (proven): 128x128 tile, all-gl_lds staging, 2-phase double buffer.
// A now bf16 (xb) -> no f32 loads, no converts in the K-loop.
__global__ __launch_bounds__(256) void gemm1_kernel(
    const bf16_t* __restrict__ xb, const bf16_t* __restrict__ W1,
    const float* __restrict__ fc1b, bf16_t* __restrict__ H0) {
  __shared__ bf16_t Alds[2][128*32];
  __shared__ bf16_t Blds[2][128*32];
  const int tid  = threadIdx.x;
  const int lane = tid & 63;
  const int wave = tid >> 6;
  const int bm = blockIdx.x, bn = blockIdx.y;

  const bf16_t* asrc0 = xb + (size_t)(bm*128 + (tid>>2))*CIN + (tid&3)*8;
  const bf16_t* asrc1 = asrc0 + (size_t)64*CIN;
  const bf16_t* bsrc0 = W1 + (size_t)(bn*128 + (tid>>2))*CIN + (tid&3)*8;
  const bf16_t* bsrc1 = bsrc0 + (size_t)64*CIN;
  const int aoff0 = tid*8;
  const int aoff1 = (tid+256)*8;

  const int quad = lane >> 4;
  const int r16  = lane & 15;
  const int wm = (wave >> 1) * 64;
  const int wn = (wave & 1) * 64;

  f32x4 acc[4][4] = {};

  // ---- prologue: stage K-step 0 into buffer 0 ----
  gl_lds16(asrc0, &Alds[0][aoff0]);
  gl_lds16(asrc1, &Alds[0][aoff1]);
  gl_lds16(bsrc0, &Blds[0][aoff0]);
  gl_lds16(bsrc1, &Blds[0][aoff1]);
  __syncthreads();

  int cur = 0;
  for (int k0 = 0; k0 < CIN; k0 += 32) {
    const int kn = k0 + 32;
    if (kn < CIN) {
      gl_lds16(asrc0 + kn, &Alds[cur^1][aoff0]);
      gl_lds16(asrc1 + kn, &Alds[cur^1][aoff1]);
      gl_lds16(bsrc0 + kn, &Blds[cur^1][aoff0]);
      gl_lds16(bsrc1 + kn, &Blds[cur^1][aoff1]);
    }
    bf16x8 af[4], bfr[4];
    #pragma unroll
    for (int mt = 0; mt < 4; mt++)
      af[mt] = *(const bf16x8*)&Alds[cur][(wm + mt*16 + r16)*32 + quad*8];
    #pragma unroll
    for (int nt = 0; nt < 4; nt++)
      bfr[nt] = *(const bf16x8*)&Blds[cur][(wn + nt*16 + r16)*32 + quad*8];
    #pragma unroll
    for (int mt = 0; mt < 4; mt++)
      #pragma unroll
      for (int nt = 0; nt < 4; nt++)
        acc[mt][nt] = __builtin_amdgcn_mfma_f32_16x16x32_bf16(af[mt], bfr[nt], acc[mt][nt], 0, 0, 0);
    __syncthreads();
    cur ^= 1;
  }

  #pragma unroll
  for (int nt = 0; nt < 4; nt++) {
    const int col = bn*128 + wn + nt*16 + r16;
    const float bias = fc1b[col];
    #pragma unroll
    for (int mt = 0; mt < 4; mt++) {
      const int row0 = bm*128 + wm + mt*16 + quad*4;
      #pragma unroll
      for (int rg = 0; rg < 4; rg++)
        H0[(size_t)(row0 + rg)*CA_ + col] = (bf16_t)(acc[mt][nt][rg] + bias);
    }
  }
}

// ---------------- fused conv v4: register-local temporal scatter, XCD-swizzled ----------------
__global__ __launch_bounds__(192) void conv_kernel(
    const bf16_t* __restrict__ H0,
    const bf16_t* __restrict__ Wtb,   // [27][384] bf16
    const float* __restrict__ beff,   // [384]
    const float* __restrict__ pwt,    // [3][384]
    const float* __restrict__ pb,     // [384]
    bf16_t* __restrict__ Z) {
  __shared__ bf16_t Wlds[27*CA_];     // 20736 B
  __shared__ float  ybuf[2][2][CA_];  // 6144 B

  const int tid = threadIdx.x;
  {
    const uint4* src = (const uint4*)Wtb;
    uint4* dst = (uint4*)Wlds;
    #pragma unroll
    for (int i = 0; i < 7; i++) {
      int idx = tid + i*192;
      if (idx < 27*CA_/8) dst[idx] = src[idx];   // 1296 x 16B
    }
  }

  const int blk  = blockIdx.x;       // 0..783
  const int b    = blk & 7;
  const int pair = blk >> 3;         // 0..97
  const int cg   = tid % 48;
  const int ct   = tid / 48;         // 0..3
  const int col  = ct >> 1;
  const int th   = ct & 1;
  const int hw   = pair*2 + col;     // 0..195
  const int h    = hw / HH, w = hw % HH;
  const int c0   = cg * 8;
  const int t0   = th * 8;

  // init y with effective bias
  float y[8][8];
  {
    f32x4 bv0 = *(const f32x4*)(beff + c0);
    f32x4 bv1 = *(const f32x4*)(beff + c0 + 4);
    #pragma unroll
    for (int i = 0; i < 8; i++) {
      #pragma unroll
      for (int c = 0; c < 4; c++) { y[i][c] = bv0[c]; y[i][c+4] = bv1[c]; }
    }
  }

  __syncthreads();   // Wlds ready

  const size_t rowstride = (size_t)196*CA_;   // elements per t-step
  const bf16_t* base_t0 = H0 + ((size_t)(b*TT + t0)*196)*CA_ + c0;
  const int tau_e_off = th ? -1 : 8;          // the one extra valid tau (relative to t0)

  for (int j = 0; j < 9; j++) {
    const int dh = j / 3, dw = j - dh*3;
    const int h2 = h + dh - 1, w2 = w + dw - 1;
    const bool ok = ((unsigned)h2 < HH) && ((unsigned)w2 < HH);
    const int sp = ok ? (h2*HH + w2) : hw;    // clamped, always in-bounds
    const float m = ok ? 1.0f : 0.0f;

    const bf16x8 wv0 = *(const bf16x8*)&Wlds[(0*9+j)*CA_ + c0];
    const bf16x8 wv1 = *(const bf16x8*)&Wlds[(1*9+j)*CA_ + c0];
    const bf16x8 wv2 = *(const bf16x8*)&Wlds[(2*9+j)*CA_ + c0];
    float mw0[8], mw1[8], mw2[8];
    #pragma unroll
    for (int c = 0; c < 8; c++) {
      mw0[c] = m * (float)wv0[c];
      mw1[c] = m * (float)wv1[c];
      mw2[c] = m * (float)wv2[c];
    }

    const bf16_t* tp = base_t0 + (size_t)sp*CA_;
    bf16x8 gv[8];
    #pragma unroll
    for (int i = 0; i < 8; i++)
      gv[i] = *(const bf16x8*)(tp + (ptrdiff_t)i*(ptrdiff_t)rowstride);
    const bf16x8 ge = *(const bf16x8*)(tp + (ptrdiff_t)tau_e_off*(ptrdiff_t)rowstride);

    // interior taus: tau = t0+i contributes to y[i-1] (w2), y[i] (w1), y[i+1] (w0)
    #pragma unroll
    for (int i = 0; i < 8; i++) {
      float gf[8];
      #pragma unroll
      for (int c = 0; c < 8; c++) gf[c] = (float)gv[i][c];
      #pragma unroll
      for (int c = 0; c < 8; c++) y[i][c] += gf[c]*mw1[c];
      if (i > 0) {
        #pragma unroll
        for (int c = 0; c < 8; c++) y[i-1][c] += gf[c]*mw2[c];
      }
      if (i < 7) {
        #pragma unroll
        for (int c = 0; c < 8; c++) y[i+1][c] += gf[c]*mw0[c];
      }
    }
    // edge tau: th=0 -> tau=t0+8 feeds y[7] via w2 ; th=1 -> tau=t0-1 feeds y[0] via w0
    {
      float gf[8];
      #pragma unroll
      for (int c = 0; c < 8; c++) gf[c] = (float)ge[c];
      if (th) {
        #pragma unroll
        for (int c = 0; c < 8; c++) y[0][c] += gf[c]*mw0[c];
      } else {
        #pragma unroll
        for (int c = 0; c < 8; c++) y[7][c] += gf[c]*mw2[c];
      }
    }
  }

  // exchange the boundary y between t-halves (for the temporal proj)
  #pragma unroll
  for (int c = 0; c < 8; c++) ybuf[col][th][c0+c] = th ? y[0][c] : y[7][c];
  __syncthreads();
  float yedge[8];
  #pragma unroll
  for (int c = 0; c < 8; c++) yedge[c] = ybuf[col][1-th][c0+c];

  // proj weights
  float p0[8], p1[8], p2[8], pbv[8];
  {
    f32x4 a0 = *(const f32x4*)(pwt + 0*CA_ + c0), a1 = *(const f32x4*)(pwt + 0*CA_ + c0 + 4);
    f32x4 b0 = *(const f32x4*)(pwt + 1*CA_ + c0), b1 = *(const f32x4*)(pwt + 1*CA_ + c0 + 4);
    f32x4 d0 = *(const f32x4*)(pwt + 2*CA_ + c0), d1 = *(const f32x4*)(pwt + 2*CA_ + c0 + 4);
    f32x4 e0 = *(const f32x4*)(pb + c0),          e1 = *(const f32x4*)(pb + c0 + 4);
    #pragma unroll
    for (int c = 0; c < 4; c++) {
      p0[c]=a0[c]; p0[c+4]=a1[c];
      p1[c]=b0[c]; p1[c+4]=b1[c];
      p2[c]=d0[c]; p2[c+4]=d1[c];
      pbv[c]=e0[c]; pbv[c+4]=e1[c];
    }
  }

  bf16_t* zbase = Z + ((size_t)(b*TT + t0)*196 + hw)*CA_ + c0;
  #pragma unroll
  for (int i = 0; i < 8; i++) {
    bf16x8 zo;
    #pragma unroll
    for (int c = 0; c < 8; c++) {
      const float ym = (i > 0) ? y[i-1][c] : (th ? yedge[c] : 0.f);
      const float yp = (i < 7) ? y[i+1][c] : (th ? 0.f : yedge[c]);
      const float z  = y[i][c] + pbv[c] + p0[c]*ym + p1[c]*y[i][c] + p2[c]*yp;
      zo[c] = (bf16_t)z;
    }
    *(bf16x8*)(zbase + (size_t)i*rowstride) = zo;
  }
}

// ---------------- GEMM2: out[xrow,c] = x[xrow,c] + Z[tok,:] . fc2_w[c,:] + fc2_b[c] ----------------
// r1 structure: 128x128 tile, 2-phase double buffer, all-gl_lds staging.
__global__ __launch_bounds__(256) void gemm2_kernel(
    const bf16_t* __restrict__ Z, const bf16_t* __restrict__ W2,
    const float* __restrict__ fc2b, const float* __restrict__ x,
    float* __restrict__ out) {
  __shared__ bf16_t Alds[2][128*32];
  __shared__ bf16_t Blds[2][128*32];
  const int tid  = threadIdx.x;
  const int lane = tid & 63;
  const int wave = tid >> 6;
  const int bm = blockIdx.x, bn = blockIdx.y;

  const bf16_t* asrc0 = Z  + (size_t)(bm*128 + (tid>>2))*CA_ + (tid&3)*8;
  const bf16_t* asrc1 = asrc0 + (size_t)64*CA_;
  const bf16_t* bsrc0 = W2 + (size_t)(bn*128 + (tid>>2))*CA_ + (tid&3)*8;
  const bf16_t* bsrc1 = bsrc0 + (size_t)64*CA_;
  const int aoff0 = tid*8;
  const int aoff1 = (tid+256)*8;

  const int quad = lane >> 4;
  const int r16  = lane & 15;
  const int wm = (wave >> 1) * 64;
  const int wn = (wave & 1) * 64;

  f32x4 acc[4][4] = {};

  // ---- prologue: stage K-step 0 into buffer 0 ----
  gl_lds16(asrc0, &Alds[0][aoff0]);
  gl_lds16(asrc1, &Alds[0][aoff1]);
  gl_lds16(bsrc0, &Blds[0][aoff0]);
  gl_lds16(bsrc1, &Blds[0][aoff1]);
  __syncthreads();

  int cur = 0;
  for (int k0 = 0; k0 < CA_; k0 += 32) {
    const int kn = k0 + 32;
    if (kn < CA_) {
      gl_lds16(asrc0 + kn, &Alds[cur^1][aoff0]);
      gl_lds16(asrc1 + kn, &Alds[cur^1][aoff1]);
      gl_lds16(bsrc0 + kn, &Blds[cur^1][aoff0]);
      gl_lds16(bsrc1 + kn, &Blds[cur^1][aoff1]);
    }
    bf16x8 af[4], bfr[4];
    #pragma unroll
    for (int mt = 0; mt < 4; mt++)
      af[mt] = *(const bf16x8*)&Alds[cur][(wm + mt*16 + r16)*32 + quad*8];
    #pragma unroll
    for (int nt = 0; nt < 4; nt++)
      bfr[nt] = *(const bf16x8*)&Blds[cur][(wn + nt*16 + r16)*32 + quad*8];
    #pragma unroll
    for (int mt = 0; mt < 4; mt++)
      #pragma unroll
      for (int nt = 0; nt < 4; nt++)
        acc[mt][nt] = __builtin_amdgcn_mfma_f32_16x16x32_bf16(af[mt], bfr[nt], acc[mt][nt], 0, 0, 0);
    __syncthreads();
    cur ^= 1;
  }

  #pragma unroll
  for (int nt = 0; nt < 4; nt++) {
    const int col = bn*128 + wn + nt*16 + r16;
    const float bias = fc2b[col];
    #pragma unroll
    for (int mt = 0; mt < 4; mt++) {
      #pragma unroll
      for (int rg = 0; rg < 4; rg++) {
        const int tok = bm*128 + wm + mt*16 + quad*4 + rg;
        const int bt  = tok / 196;
        const size_t o = (size_t)(tok + bt + 1)*CIN + col;
        out[o] = x[o] + acc[mt][nt][rg] + bias;
      }
    }
  }
}

extern "C" void kernel_launch(void* const* d_in, const int* in_sizes, int n_in,
                              void* d_out, int out_size, void* d_ws, size_t ws_size,
                              hipStream_t stream) {
  (void)in_sizes; (void)n_in; (void)out_size; (void)ws_size;
  const float* x    = (const float*)d_in[0];
  const float* fc1w = (const float*)d_in[1];
  const float* fc1b = (const float*)d_in[2];
  const float* c1w  = (const float*)d_in[3];
  const float* c1b  = (const float*)d_in[4];
  const float* c2w  = (const float*)d_in[5];
  const float* c2b  = (const float*)d_in[6];
  const float* c3w  = (const float*)d_in[7];
  const float* c3b  = (const float*)d_in[8];
  const float* pw   = (const float*)d_in[9];
  const float* pb   = (const float*)d_in[10];
  const float* fc2w = (const float*)d_in[11];
  const float* fc2b = (const float*)d_in[12];
  float* out = (float*)d_out;

  char* ws = (char*)d_ws;
  bf16_t* W1   = (bf16_t*)(ws);                    // 589824
  bf16_t* W2   = (bf16_t*)(ws + 589824);           // 589824
  bf16_t* Wtb  = (bf16_t*)(ws + 1179648);          // 20736
  float*  beff = (float*) (ws + 1200384);          // 1536
  float*  pwt  = (float*) (ws + 1201920);          // 4608
  bf16_t* xb   = (bf16_t*)(ws + 1206528);          // 38535168 (dead after gemm1)
  bf16_t* Z    = (bf16_t*)(ws + 1206528);          // 19267584 (aliases xb; born in conv)
  bf16_t* H0   = (bf16_t*)(ws + 39741696);         // 19267584 -> total 59009280 bytes

  prep_weights_kernel<<<dim3(2), dim3(192), 0, stream>>>(
      c1w, c1b, c2w, c2b, c3w, c3b, pw, Wtb, beff, pwt);
  convert_w_kernel<<<dim3(4096), dim3(256), 0, stream>>>(fc1w, fc2w, x, out, W1, W2, xb);
  gemm1_kernel<<<dim3(196, 3), dim3(256), 0, stream>>>(xb, W1, fc1b, H0);
  conv_kernel<<<dim3(784), dim3(192), 0, stream>>>(H0, Wtb, beff, pwt, pb, Z);
  gemm2_kernel<<<dim3(196, 6), dim3(256), 0, stream>>>(Z, W2, fc2b, x, out);
}